// Round 15
// baseline (251.738 us; speedup 1.0000x reference)
//
#include <hip/hip_runtime.h>
#include <hip/hip_fp16.h>

#define EPS 1e-5f
#define NREP 16       // colsum/sumsq replicas (breaks the R8/R9 atomic storm)
#define REPSTRIDE 132 // floats per replica row; 132 % 16 = 4 staggers L2 lines
#define MAXDEG 48     // padded-CSR slots/node; deg ~ Poisson(12), P(any>48) ~ 1e-10

typedef _Float16 half8_t __attribute__((ext_vector_type(8)));
typedef float floatx4 __attribute__((ext_vector_type(4)));

// ---------------------------------------------------------------------------
// K1 (R18): FUSED scatter + LDS-LESS gemm. R16 retro-analysis: fusion was +8us
// because the 34.8KB static LDS was allocated by EVERY block, halving
// scatter-role occupancy (4 blocks/CU vs 8). This version declares ZERO LDS:
// gemm reads B-fragments straight from global W (64KB, L1/L2-hot; 2x float4 +
// cvt per fragment). Scatter role keeps full occupancy; roles interleave 3:1
// (2344 scatter : 782 gemm) so both co-reside from t=0. gemm stores UNSCALED
// fp16(xw) (no cursor dependency); dinv applied by scale_kernel after.
//
// gemm layouts (m89/m92-verified):
//   A frag (16x32): lane l elem j -> A[l&15][8*(l>>4)+j]
//   B frag (32x16): lane l elem j -> B[8*(l>>4)+j][l&15] = W[l&15 col][k]
//   D frag (16x16): lane l reg  r -> D[4*(l>>4)+r][l&15]
__global__ __launch_bounds__(256) void build_kernel(
    const int* __restrict__ row, const int* __restrict__ col,
    int* __restrict__ cursor, int* __restrict__ csr, int E, int nScatter,
    const float* __restrict__ x, const float* __restrict__ W,
    __half* __restrict__ xsh, int N, int nGemm) {
    int b = blockIdx.x;
    int tid = threadIdx.x;

    if ((b & 3) != 3) {
        // ----- scatter role: 3 of every 4 blocks (full occupancy, no LDS) -----
        int sb = b - ((b + 1) >> 2);       // sequential scatter block index
        if (sb >= nScatter) return;
        int e = sb * 256 + tid;
        if (e < E) {
            int c = col[e];
            int pos = atomicAdd(&cursor[c], 1);
            if (pos < MAXDEG) csr[c * MAXDEG + pos] = row[e];  // guard unreachable
        }
        return;
    }

    // ----- gemm role: every 4th block -----
    int gb = b >> 2;
    if (gb >= nGemm) return;

    int w  = tid >> 6;   // wave 0..3
    int l  = tid & 63;
    int lr = l & 15;     // A row / B col within fragment
    int kb = l >> 4;     // k-block 0..3

    int rowA = gb * 64 + w * 16 + lr;
    const float4* xr = (const float4*)&x[(size_t)min(rowA, N - 1) * 128];

    // lane's 32 x-floats: for kk in 0..3, floats [32*kk + 8*kb, +8)
    float4 xv[8];
#pragma unroll
    for (int kk = 0; kk < 4; ++kk) {
        xv[2 * kk]     = xr[8 * kk + 2 * kb];
        xv[2 * kk + 1] = xr[8 * kk + 2 * kb + 1];
    }
    half8_t a[4];
#pragma unroll
    for (int kk = 0; kk < 4; ++kk) {
        float4 v0 = xv[2 * kk], v1 = xv[2 * kk + 1];
        half8_t h;
        h[0] = (_Float16)v0.x; h[1] = (_Float16)v0.y;
        h[2] = (_Float16)v0.z; h[3] = (_Float16)v0.w;
        h[4] = (_Float16)v1.x; h[5] = (_Float16)v1.y;
        h[6] = (_Float16)v1.z; h[7] = (_Float16)v1.w;
        a[kk] = h;
    }

    floatx4 acc[8];
#pragma unroll
    for (int t = 0; t < 8; ++t) acc[t] = (floatx4){0.f, 0.f, 0.f, 0.f};

    // B-fragments direct from global W (L1/L2-hot): per (t,kk) thread needs
    // W[16t+lr][32kk+8kb .. +8) = float4 pair at W4[(16t+lr)*32 + 8kk + 2kb]
    const float4* W4 = (const float4*)W;
#pragma unroll
    for (int t = 0; t < 8; ++t) {
        int wbase = (16 * t + lr) * 32;
#pragma unroll
        for (int kk = 0; kk < 4; ++kk) {
            float4 w0 = W4[wbase + 8 * kk + 2 * kb];
            float4 w1 = W4[wbase + 8 * kk + 2 * kb + 1];
            half8_t bb;
            bb[0] = (_Float16)w0.x; bb[1] = (_Float16)w0.y;
            bb[2] = (_Float16)w0.z; bb[3] = (_Float16)w0.w;
            bb[4] = (_Float16)w1.x; bb[5] = (_Float16)w1.y;
            bb[6] = (_Float16)w1.z; bb[7] = (_Float16)w1.w;
            acc[t] = __builtin_amdgcn_mfma_f32_16x16x32_f16(a[kk], bb, acc[t], 0, 0, 0);
        }
    }

    // epilogue: UNSCALED store (dinv applied by scale_kernel)
    int rbase = gb * 64 + w * 16 + 4 * kb;
#pragma unroll
    for (int r = 0; r < 4; ++r) {
        int grow = rbase + r;
        if (grow < N) {
#pragma unroll
            for (int t = 0; t < 8; ++t)
                xsh[(size_t)grow * 128 + 16 * t + lr] = __float2half(acc[t][r]);
        }
    }
}

// ---------------------------------------------------------------------------
// K2 (R18): in-place dinv scaling of xsh. 25.6MB r+w ~ 5us. One uint4
// (8 halves) per thread; cursor[n] is a 16-lane broadcast L2 hit.
__global__ void scale_kernel(__half* __restrict__ xsh, const int* __restrict__ cursor, int N) {
    int i = blockIdx.x * blockDim.x + threadIdx.x;
    if (i >= N * 16) return;
    int n = i >> 4;
    float dv = rsqrtf((float)(cursor[n] + 1));
    uint4* p = (uint4*)xsh;
    uint4 v = p[i];
    __half2* h = (__half2*)&v;
#pragma unroll
    for (int t = 0; t < 4; ++t) {
        float2 f = __half22float2(h[t]);
        h[t] = __floats2half2_rn(f.x * dv, f.y * dv);
    }
    p[i] = v;
}

// ---------------------------------------------------------------------------
// K5 (R15-FROZEN): clamped-16 gather, plain stores — best measured (48.5us).
// R17's nontemporal stores REVERTED: FETCH 66->63.5MB but dur 48.5->52.4
// (write-allocate eviction disproven; NT store path slower). Five gather
// experiments done; structure frozen.
__global__ void gather_kernel(const __half2* __restrict__ xs2, const int* __restrict__ cursor,
                              const int* __restrict__ csr,
                              float* __restrict__ pre, float* __restrict__ colrep,
                              float* __restrict__ ssrep, int N) {
    __shared__ float scol[128];
    __shared__ float sss;
    if (threadIdx.x < 128) scol[threadIdx.x] = 0.f;
    if (threadIdx.x == 0) sss = 0.f;
    __syncthreads();

    int lane = threadIdx.x & 63;
    int wid = (blockIdx.x * blockDim.x + threadIdx.x) >> 6;
    int nw  = (gridDim.x * blockDim.x) >> 6;
    float2* pre2 = (float2*)pre;
    float csx = 0.f, csy = 0.f, ss = 0.f;

    for (int n = wid; n < N; n += nw) {
        int deg = cursor[n];
        int e = min(deg, MAXDEG);
        const int* cs = &csr[n * MAXDEG];
        float2 acc = __half22float2(xs2[n * 64 + lane]);  // self loop term
        for (int base = 0; base < e; base += 16) {
            int idx[16];
#pragma unroll
            for (int t = 0; t < 16; ++t) idx[t] = cs[min(base + t, e - 1)];
            __half2 a[16];
#pragma unroll
            for (int t = 0; t < 16; ++t) a[t] = xs2[idx[t] * 64 + lane];
#pragma unroll
            for (int t = 0; t < 16; ++t) {
                float m = (base + t < e) ? 1.f : 0.f;
                float2 f = __half22float2(a[t]);
                acc.x += m * f.x; acc.y += m * f.y;
            }
        }
        float dv = rsqrtf((float)(deg + 1));
        float vx = acc.x * dv, vy = acc.y * dv;
        pre2[n * 64 + lane] = make_float2(vx, vy);
        csx += vx; csy += vy; ss += vx * vx + vy * vy;
    }

    // block-level reduction, then one atomic per slot into replica blockIdx&15
    atomicAdd(&scol[2 * lane], csx);
    atomicAdd(&scol[2 * lane + 1], csy);
    for (int d = 32; d > 0; d >>= 1) ss += __shfl_down(ss, d);
    if (lane == 0) atomicAdd(&sss, ss);
    __syncthreads();
    int rep = blockIdx.x & (NREP - 1);
    if (threadIdx.x < 128) atomicAdd(&colrep[rep * REPSTRIDE + threadIdx.x], scol[threadIdx.x]);
    if (threadIdx.x == 128) atomicAdd(&ssrep[rep], sss);
}

// ---------------------------------------------------------------------------
// K8: FUSED params + apply. Each block sums the 16 replicas to derive m[j]
// and s (all L2-hot), then: y=(v-m_j)*s; out = y>0 ? 2y : y.
__global__ void final_kernel(float* __restrict__ out, const float* __restrict__ colrep,
                             const float* __restrict__ ssrep, int N, int total) {
    __shared__ float sm[128];
    __shared__ float red[128];
    __shared__ float sscale;
    int t = threadIdx.x;
    if (t < 128) {
        float cs = 0.f;
#pragma unroll
        for (int r = 0; r < NREP; ++r) cs += colrep[r * REPSTRIDE + t];
        float m = cs / (float)N;
        sm[t] = m;
        red[t] = m * m;
    }
    __syncthreads();
    for (int d = 64; d > 0; d >>= 1) {
        if (t < d) red[t] += red[t + d];
        __syncthreads();
    }
    if (t == 0) {
        float sq = 0.f;
#pragma unroll
        for (int r = 0; r < NREP; ++r) sq += ssrep[r];
        float tot = sq - (float)N * red[0];  // sum (out - m)^2
        sscale = rsqrtf(EPS + tot / (float)N);
    }
    __syncthreads();
    float s = sscale;
    int tid = blockIdx.x * blockDim.x + threadIdx.x;
    int stride = gridDim.x * blockDim.x;
    for (int i = tid; i < total; i += stride) {
        float y = (out[i] - sm[i & 127]) * s;
        out[i] = y > 0.f ? 2.f * y : y;
    }
}

// ---------------------------------------------------------------------------
extern "C" void kernel_launch(void* const* d_in, const int* in_sizes, int n_in,
                              void* d_out, int out_size, void* d_ws, size_t ws_size,
                              hipStream_t stream) {
    const float* x = (const float*)d_in[0];
    const float* W = (const float*)d_in[1];
    const int* ei  = (const int*)d_in[2];
    int N = in_sizes[0] / 128;
    int E = in_sizes[2] / 2;
    const int* row = ei;        // edge_index[0] = source
    const int* col = ei + E;    // edge_index[1] = aggregation target
    float* out = (float*)d_out;

    // workspace layout: ~12.8MB (xsh) + 0.2 (cursor) + 9.6 (csr) ~= 22.8 MB
    __half* xsh      = (__half*)d_ws;                  // N*128 halves (interleaved)
    int*   cursor    = (int*)((float*)d_ws + (size_t)N * 64);  // N      [zeroed]
    float* colrep    = (float*)(cursor + N);           // NREP*REPSTRIDE [zeroed]
    float* ssrep     = colrep + NREP * REPSTRIDE;      // NREP           [zeroed]
    int*   csr       = (int*)(ssrep + NREP);           // N*MAXDEG

    hipMemsetAsync(cursor, 0, (size_t)(N + NREP * REPSTRIDE + NREP) * 4, stream);

    int nScatter = (E + 255) / 256;     // 2344
    int nGemm    = (N + 63) / 64;       // 782
    int nsBlk    = (nScatter + 2) / 3;  // 782
    int tot      = 4 * (nGemm > nsBlk ? nGemm : nsBlk);  // 3:1 interleave

    build_kernel  <<<tot, 256, 0, stream>>>(row, col, cursor, csr, E, nScatter,
                                            x, W, xsh, N, nGemm);
    scale_kernel  <<<(N * 16 + 255) / 256, 256, 0, stream>>>(xsh, cursor, N);
    gather_kernel <<<2048, 256, 0, stream>>>((const __half2*)xsh, cursor, csr,
                                             out, colrep, ssrep, N);
    final_kernel  <<<1024, 256, 0, stream>>>(out, colrep, ssrep, N, N * 128);
}

// Round 16
// 175.622 us; speedup vs baseline: 1.4334x; 1.4334x over previous
//
#include <hip/hip_runtime.h>
#include <hip/hip_fp16.h>

#define EPS 1e-5f
#define NREP 16       // colsum/sumsq replicas (breaks the R8/R9 atomic storm)
#define REPSTRIDE 132 // floats per replica row; 132 % 16 = 4 staggers L2 lines
#define MAXDEG 48     // padded-CSR slots/node; deg ~ Poisson(12), P(any>48) ~ 1e-10

typedef _Float16 half8_t __attribute__((ext_vector_type(8)));
typedef float floatx4 __attribute__((ext_vector_type(4)));

// ---------------------------------------------------------------------------
// K1 (R11, FINAL): single-pass padded-CSR build. Fusion with gemm tried twice
// and permanently abandoned: R16 (edge-side dinv enabler) +34us in dependent
// cursor loads; R18 (LDS-less gemm enabler) +80us — W fragments are
// lane-divergent, so W staging in LDS is load-bearing and the gemm role
// cannot drop it. Node-side dinv needs complete cursor -> scatter stays a
// separate dispatch.
__global__ void scatter_kernel(const int* __restrict__ row, const int* __restrict__ col,
                               int* __restrict__ cursor, int* __restrict__ csr, int E) {
    int e = blockIdx.x * blockDim.x + threadIdx.x;
    if (e < E) {
        int c = col[e];
        int pos = atomicAdd(&cursor[c], 1);
        if (pos < MAXDEG) csr[c * MAXDEG + pos] = row[e];  // guard unreachable in practice
    }
}

// ---------------------------------------------------------------------------
// K4 (R10, FINAL): xs = fp16( (x @ W.T) * dinv[row] ) — MFMA, W staged once
// per block into padded LDS. Interleaved N*128 xsh layout (R12/R13 slab
// experiments failed: gather reuse/working-set ~3x -> multi-pass multiplies
// compulsory fills). dinv from cursor in the epilogue (node-side scaling).
//
// Layouts (m89/m92-verified conventions):
//   A frag (16x32): lane l elem j -> A[l&15][8*(l>>4)+j]   (contiguous-8 in K)
//   B frag (32x16): lane l elem j -> B[8*(l>>4)+j][l&15]
//   D frag (16x16): lane l reg  r -> D[4*(l>>4)+r][l&15]
// B[k][col] = W[col][k], so LDS = fp16 W row-major: frag load = ds_read_b128 of
// sw[col][8*(l>>4)]. Pad row to 136 halves: stride 272B = 68 dwords == 4 mod 32
// -> perfect bank distribution for b128 reads, and 272 = 17*16 keeps 16B align.
// x has zero reuse -> direct global float4 loads + in-register f32->f16 cvt.
__global__ __launch_bounds__(256) void gemm_kernel(
    const float* __restrict__ x, const float* __restrict__ W,
    const int* __restrict__ cursor, __half* __restrict__ xsh, int N) {
    __shared__ _Float16 sw[128][136];  // 34.8 KB

    int tid = threadIdx.x;
    // stage W as fp16: 4096 float4 loads, 16 per thread
#pragma unroll
    for (int t = 0; t < 16; ++t) {
        int idx = tid + t * 256;      // [0, 4096)
        int j = idx >> 5;             // W row (output col) 0..127
        int k4 = idx & 31;            // float4 within row
        float4 v = ((const float4*)W)[idx];
        _Float16* d = &sw[j][k4 * 4];
        d[0] = (_Float16)v.x; d[1] = (_Float16)v.y;
        d[2] = (_Float16)v.z; d[3] = (_Float16)v.w;
    }
    __syncthreads();

    int w  = tid >> 6;   // wave 0..3
    int l  = tid & 63;
    int lr = l & 15;     // A row / B col within fragment
    int kb = l >> 4;     // k-block 0..3

    int rowA = blockIdx.x * 64 + w * 16 + lr;
    const float4* xr = (const float4*)&x[(size_t)min(rowA, N - 1) * 128];

    // lane's 32 x-floats: for kk in 0..3, floats [32*kk + 8*kb, +8)
    float4 xv[8];
#pragma unroll
    for (int kk = 0; kk < 4; ++kk) {
        xv[2 * kk]     = xr[8 * kk + 2 * kb];
        xv[2 * kk + 1] = xr[8 * kk + 2 * kb + 1];
    }
    half8_t a[4];
#pragma unroll
    for (int kk = 0; kk < 4; ++kk) {
        float4 v0 = xv[2 * kk], v1 = xv[2 * kk + 1];
        half8_t h;
        h[0] = (_Float16)v0.x; h[1] = (_Float16)v0.y;
        h[2] = (_Float16)v0.z; h[3] = (_Float16)v0.w;
        h[4] = (_Float16)v1.x; h[5] = (_Float16)v1.y;
        h[6] = (_Float16)v1.z; h[7] = (_Float16)v1.w;
        a[kk] = h;
    }

    floatx4 acc[8];
#pragma unroll
    for (int t = 0; t < 8; ++t) acc[t] = (floatx4){0.f, 0.f, 0.f, 0.f};

#pragma unroll
    for (int kk = 0; kk < 4; ++kk) {
#pragma unroll
        for (int t = 0; t < 8; ++t) {
            half8_t b = *(const half8_t*)&sw[16 * t + lr][32 * kk + 8 * kb];
            acc[t] = __builtin_amdgcn_mfma_f32_16x16x32_f16(a[kk], b, acc[t], 0, 0, 0);
        }
    }

    // epilogue: D row (in-tile) = 4*kb + r, col = 16*t + lr
    int rbase = blockIdx.x * 64 + w * 16 + 4 * kb;
    float dv[4];
#pragma unroll
    for (int r = 0; r < 4; ++r)
        dv[r] = (rbase + r < N) ? rsqrtf((float)(cursor[rbase + r] + 1)) : 0.f;
#pragma unroll
    for (int r = 0; r < 4; ++r) {
        int grow = rbase + r;
        if (grow < N) {
#pragma unroll
            for (int t = 0; t < 8; ++t)
                xsh[(size_t)grow * 128 + 16 * t + lr] = __float2half(acc[t][r] * dv[r]);
        }
    }
}

// ---------------------------------------------------------------------------
// K5 (R15, FROZEN): clamped-16 gather, plain stores — best measured (48.5us).
// Experiment history: R11 8/4/serial batches 52us; R12/R13 multi-pass slicing
// +100us (compulsory-miss dominated); R14 wide-lane 62us (divergence +
// occupancy loss); R15 clamped-16 48.5us (serial tail removed); R16 edge-side
// dinv +34us (dependent cursor loads); R17 nontemporal stores +4us (NT store
// path slower; write-allocate eviction disproven, FETCH only 66->63.5MB).
// Floor for this access pattern ~ latency x E[ceil(deg/16)] at ~44% occ.
__global__ void gather_kernel(const __half2* __restrict__ xs2, const int* __restrict__ cursor,
                              const int* __restrict__ csr,
                              float* __restrict__ pre, float* __restrict__ colrep,
                              float* __restrict__ ssrep, int N) {
    __shared__ float scol[128];
    __shared__ float sss;
    if (threadIdx.x < 128) scol[threadIdx.x] = 0.f;
    if (threadIdx.x == 0) sss = 0.f;
    __syncthreads();

    int lane = threadIdx.x & 63;
    int wid = (blockIdx.x * blockDim.x + threadIdx.x) >> 6;
    int nw  = (gridDim.x * blockDim.x) >> 6;
    float2* pre2 = (float2*)pre;
    float csx = 0.f, csy = 0.f, ss = 0.f;

    for (int n = wid; n < N; n += nw) {
        int deg = cursor[n];
        int e = min(deg, MAXDEG);
        const int* cs = &csr[n * MAXDEG];
        float2 acc = __half22float2(xs2[n * 64 + lane]);  // self loop term
        for (int base = 0; base < e; base += 16) {
            int idx[16];
#pragma unroll
            for (int t = 0; t < 16; ++t) idx[t] = cs[min(base + t, e - 1)];
            __half2 a[16];
#pragma unroll
            for (int t = 0; t < 16; ++t) a[t] = xs2[idx[t] * 64 + lane];
#pragma unroll
            for (int t = 0; t < 16; ++t) {
                float m = (base + t < e) ? 1.f : 0.f;
                float2 f = __half22float2(a[t]);
                acc.x += m * f.x; acc.y += m * f.y;
            }
        }
        float dv = rsqrtf((float)(deg + 1));
        float vx = acc.x * dv, vy = acc.y * dv;
        pre2[n * 64 + lane] = make_float2(vx, vy);
        csx += vx; csy += vy; ss += vx * vx + vy * vy;
    }

    // block-level reduction, then one atomic per slot into replica blockIdx&15
    atomicAdd(&scol[2 * lane], csx);
    atomicAdd(&scol[2 * lane + 1], csy);
    for (int d = 32; d > 0; d >>= 1) ss += __shfl_down(ss, d);
    if (lane == 0) atomicAdd(&sss, ss);
    __syncthreads();
    int rep = blockIdx.x & (NREP - 1);
    if (threadIdx.x < 128) atomicAdd(&colrep[rep * REPSTRIDE + threadIdx.x], scol[threadIdx.x]);
    if (threadIdx.x == 128) atomicAdd(&ssrep[rep], sss);
}

// ---------------------------------------------------------------------------
// K8: FUSED params + apply. Each block sums the 16 replicas to derive m[j]
// and s (all L2-hot), then: y=(v-m_j)*s; out = y>0 ? 2y : y.
__global__ void final_kernel(float* __restrict__ out, const float* __restrict__ colrep,
                             const float* __restrict__ ssrep, int N, int total) {
    __shared__ float sm[128];
    __shared__ float red[128];
    __shared__ float sscale;
    int t = threadIdx.x;
    if (t < 128) {
        float cs = 0.f;
#pragma unroll
        for (int r = 0; r < NREP; ++r) cs += colrep[r * REPSTRIDE + t];
        float m = cs / (float)N;
        sm[t] = m;
        red[t] = m * m;
    }
    __syncthreads();
    for (int d = 64; d > 0; d >>= 1) {
        if (t < d) red[t] += red[t + d];
        __syncthreads();
    }
    if (t == 0) {
        float sq = 0.f;
#pragma unroll
        for (int r = 0; r < NREP; ++r) sq += ssrep[r];
        float tot = sq - (float)N * red[0];  // sum (out - m)^2
        sscale = rsqrtf(EPS + tot / (float)N);
    }
    __syncthreads();
    float s = sscale;
    int tid = blockIdx.x * blockDim.x + threadIdx.x;
    int stride = gridDim.x * blockDim.x;
    for (int i = tid; i < total; i += stride) {
        float y = (out[i] - sm[i & 127]) * s;
        out[i] = y > 0.f ? 2.f * y : y;
    }
}

// ---------------------------------------------------------------------------
extern "C" void kernel_launch(void* const* d_in, const int* in_sizes, int n_in,
                              void* d_out, int out_size, void* d_ws, size_t ws_size,
                              hipStream_t stream) {
    const float* x = (const float*)d_in[0];
    const float* W = (const float*)d_in[1];
    const int* ei  = (const int*)d_in[2];
    int N = in_sizes[0] / 128;
    int E = in_sizes[2] / 2;
    const int* row = ei;        // edge_index[0] = source
    const int* col = ei + E;    // edge_index[1] = aggregation target
    float* out = (float*)d_out;

    // workspace layout: ~12.8MB (xsh) + 0.2 (cursor) + 9.6 (csr) ~= 22.8 MB
    __half* xsh      = (__half*)d_ws;                  // N*128 halves (interleaved)
    int*   cursor    = (int*)((float*)d_ws + (size_t)N * 64);  // N      [zeroed]
    float* colrep    = (float*)(cursor + N);           // NREP*REPSTRIDE [zeroed]
    float* ssrep     = colrep + NREP * REPSTRIDE;      // NREP           [zeroed]
    int*   csr       = (int*)(ssrep + NREP);           // N*MAXDEG

    hipMemsetAsync(cursor, 0, (size_t)(N + NREP * REPSTRIDE + NREP) * 4, stream);

    scatter_kernel<<<(E + 255) / 256, 256, 0, stream>>>(row, col, cursor, csr, E);
    gemm_kernel   <<<(N + 63) / 64, 256, 0, stream>>>(x, W, cursor, xsh, N);
    gather_kernel <<<2048, 256, 0, stream>>>((const __half2*)xsh, cursor, csr,
                                             out, colrep, ssrep, N);
    final_kernel  <<<1024, 256, 0, stream>>>(out, colrep, ssrep, N, N * 128);
}

// Round 17
// 174.563 us; speedup vs baseline: 1.4421x; 1.0061x over previous
//
#include <hip/hip_runtime.h>
#include <hip/hip_fp16.h>

#define EPS 1e-5f
#define NREP 16       // colsum/sumsq replicas (breaks the R8/R9 atomic storm)
#define REPSTRIDE 132 // floats per replica row; 132 % 16 = 4 staggers L2 lines
#define MAXDEG 48     // padded-CSR slots/node; deg ~ Poisson(12), P(any>48) ~ 1e-10

typedef _Float16 half8_t __attribute__((ext_vector_type(8)));
typedef float floatx4 __attribute__((ext_vector_type(4)));

// ---------------------------------------------------------------------------
// K1 (R11, FINAL): single-pass padded-CSR build. Fusion with gemm tried twice
// and permanently abandoned: R16 (edge-side dinv enabler) +34us in dependent
// cursor loads; R18 (LDS-less gemm enabler) +80us — W fragments are
// lane-divergent, so W staging in LDS is load-bearing.
__global__ void scatter_kernel(const int* __restrict__ row, const int* __restrict__ col,
                               int* __restrict__ cursor, int* __restrict__ csr, int E) {
    int e = blockIdx.x * blockDim.x + threadIdx.x;
    if (e < E) {
        int c = col[e];
        int pos = atomicAdd(&cursor[c], 1);
        if (pos < MAXDEG) csr[c * MAXDEG + pos] = row[e];  // guard unreachable in practice
    }
}

// ---------------------------------------------------------------------------
// K4 (R10, FINAL): xs = fp16( (x @ W.T) * dinv[row] ) — MFMA, W staged once
// per block into padded LDS. Interleaved N*128 xsh layout. dinv from cursor
// in the epilogue (node-side scaling).
//
// Layouts (m89/m92-verified conventions):
//   A frag (16x32): lane l elem j -> A[l&15][8*(l>>4)+j]   (contiguous-8 in K)
//   B frag (32x16): lane l elem j -> B[8*(l>>4)+j][l&15]
//   D frag (16x16): lane l reg  r -> D[4*(l>>4)+r][l&15]
// B[k][col] = W[col][k], so LDS = fp16 W row-major: frag load = ds_read_b128 of
// sw[col][8*(l>>4)]. Pad row to 136 halves: stride 272B = 68 dwords == 4 mod 32
// -> conflict-free b128 reads. x has zero reuse -> direct float4 + in-reg cvt.
__global__ __launch_bounds__(256) void gemm_kernel(
    const float* __restrict__ x, const float* __restrict__ W,
    const int* __restrict__ cursor, __half* __restrict__ xsh, int N) {
    __shared__ _Float16 sw[128][136];  // 34.8 KB

    int tid = threadIdx.x;
    // stage W as fp16: 4096 float4 loads, 16 per thread
#pragma unroll
    for (int t = 0; t < 16; ++t) {
        int idx = tid + t * 256;      // [0, 4096)
        int j = idx >> 5;             // W row (output col) 0..127
        int k4 = idx & 31;            // float4 within row
        float4 v = ((const float4*)W)[idx];
        _Float16* d = &sw[j][k4 * 4];
        d[0] = (_Float16)v.x; d[1] = (_Float16)v.y;
        d[2] = (_Float16)v.z; d[3] = (_Float16)v.w;
    }
    __syncthreads();

    int w  = tid >> 6;   // wave 0..3
    int l  = tid & 63;
    int lr = l & 15;     // A row / B col within fragment
    int kb = l >> 4;     // k-block 0..3

    int rowA = blockIdx.x * 64 + w * 16 + lr;
    const float4* xr = (const float4*)&x[(size_t)min(rowA, N - 1) * 128];

    float4 xv[8];
#pragma unroll
    for (int kk = 0; kk < 4; ++kk) {
        xv[2 * kk]     = xr[8 * kk + 2 * kb];
        xv[2 * kk + 1] = xr[8 * kk + 2 * kb + 1];
    }
    half8_t a[4];
#pragma unroll
    for (int kk = 0; kk < 4; ++kk) {
        float4 v0 = xv[2 * kk], v1 = xv[2 * kk + 1];
        half8_t h;
        h[0] = (_Float16)v0.x; h[1] = (_Float16)v0.y;
        h[2] = (_Float16)v0.z; h[3] = (_Float16)v0.w;
        h[4] = (_Float16)v1.x; h[5] = (_Float16)v1.y;
        h[6] = (_Float16)v1.z; h[7] = (_Float16)v1.w;
        a[kk] = h;
    }

    floatx4 acc[8];
#pragma unroll
    for (int t = 0; t < 8; ++t) acc[t] = (floatx4){0.f, 0.f, 0.f, 0.f};

#pragma unroll
    for (int kk = 0; kk < 4; ++kk) {
#pragma unroll
        for (int t = 0; t < 8; ++t) {
            half8_t b = *(const half8_t*)&sw[16 * t + lr][32 * kk + 8 * kb];
            acc[t] = __builtin_amdgcn_mfma_f32_16x16x32_f16(a[kk], b, acc[t], 0, 0, 0);
        }
    }

    // epilogue: D row (in-tile) = 4*kb + r, col = 16*t + lr
    int rbase = blockIdx.x * 64 + w * 16 + 4 * kb;
    float dv[4];
#pragma unroll
    for (int r = 0; r < 4; ++r)
        dv[r] = (rbase + r < N) ? rsqrtf((float)(cursor[rbase + r] + 1)) : 0.f;
#pragma unroll
    for (int r = 0; r < 4; ++r) {
        int grow = rbase + r;
        if (grow < N) {
#pragma unroll
            for (int t = 0; t < 8; ++t)
                xsh[(size_t)grow * 128 + 16 * t + lr] = __float2half(acc[t][r] * dv[r]);
        }
    }
}

// ---------------------------------------------------------------------------
// K5 (R20): clamped-16 gather + CROSS-ITERATION PREFETCH. R15's clamped-16
// (48.5us, verified) killed the intra-node serial tail; this kills the
// per-node PROLOGUE chain (cursor[n] ~200cy -> cs[0..15] line ~200-600cy ->
// gathers ~600cy). While node n's gathers are in flight, we issue node
// (n+nw)'s cursor, self-row, and raw first-16 csr slots as INDEPENDENT loads
// (slots 0..15 of the 48-slot bucket are always in-bounds; contents may be
// poison for t>=deg). At use time batch-0 picks (t<e)? idx0[t] : idx0[0] —
// masked lanes re-fetch a line already in flight (no extra traffic), and the
// select is register-only. Per-node critical path ~ 1 gather latency. Nodes
// with deg>16 (~10%) run the R15 clamped path for batches 1+.
// Prior failures kept for the record: multi-pass slicing +100us (R12/R13),
// wide-lane +13us (R14), edge-side dinv +34us (R16), NT stores +4us (R17).
// Pre-commit: if gather >= 46us, latency structure is exhausted -> roofline.
__global__ void gather_kernel(const __half2* __restrict__ xs2, const int* __restrict__ cursor,
                              const int* __restrict__ csr,
                              float* __restrict__ pre, float* __restrict__ colrep,
                              float* __restrict__ ssrep, int N) {
    __shared__ float scol[128];
    __shared__ float sss;
    if (threadIdx.x < 128) scol[threadIdx.x] = 0.f;
    if (threadIdx.x == 0) sss = 0.f;
    __syncthreads();

    int lane = threadIdx.x & 63;
    int wid = (blockIdx.x * blockDim.x + threadIdx.x) >> 6;
    int nw  = (gridDim.x * blockDim.x) >> 6;
    float2* pre2 = (float2*)pre;
    float csx = 0.f, csy = 0.f, ss = 0.f;

    int n = wid;
    int pDeg = 0;
    __half2 pSelf = __half2{};
    int pIdx[16];
#pragma unroll
    for (int t = 0; t < 16; ++t) pIdx[t] = 0;
    if (n < N) {                      // prologue prefetch for the first node
        pDeg = cursor[n];
        pSelf = xs2[n * 64 + lane];
        const int* cs0 = &csr[n * MAXDEG];
#pragma unroll
        for (int t = 0; t < 16; ++t) pIdx[t] = cs0[t];
    }

    for (; n < N; n += nw) {
        int deg = pDeg;
        __half2 selfh = pSelf;
        int idx0[16];
#pragma unroll
        for (int t = 0; t < 16; ++t) idx0[t] = pIdx[t];

        // issue next node's prefetch NOW — retires under this node's gathers
        int nn = n + nw;
        if (nn < N) {
            pDeg = cursor[nn];
            pSelf = xs2[nn * 64 + lane];
            const int* ncs = &csr[nn * MAXDEG];
#pragma unroll
            for (int t = 0; t < 16; ++t) pIdx[t] = ncs[t];
        }

        int e = min(deg, MAXDEG);
        float2 acc = __half22float2(selfh);   // self loop term
        if (e > 0) {
            // batch 0 from prefetched indices (register-only select)
            __half2 a[16];
#pragma unroll
            for (int t = 0; t < 16; ++t) {
                int ix = (t < e) ? idx0[t] : idx0[0];
                a[t] = xs2[ix * 64 + lane];
            }
#pragma unroll
            for (int t = 0; t < 16; ++t) {
                float m = (t < e) ? 1.f : 0.f;
                float2 f = __half22float2(a[t]);
                acc.x += m * f.x; acc.y += m * f.y;
            }
            // batches 1+ (deg > 16, ~10% of nodes): R15 clamped path
            const int* cs = &csr[n * MAXDEG];
            for (int base = 16; base < e; base += 16) {
                int idx[16];
#pragma unroll
                for (int t = 0; t < 16; ++t) idx[t] = cs[min(base + t, e - 1)];
                __half2 b[16];
#pragma unroll
                for (int t = 0; t < 16; ++t) b[t] = xs2[idx[t] * 64 + lane];
#pragma unroll
                for (int t = 0; t < 16; ++t) {
                    float m = (base + t < e) ? 1.f : 0.f;
                    float2 f = __half22float2(b[t]);
                    acc.x += m * f.x; acc.y += m * f.y;
                }
            }
        }
        float dv = rsqrtf((float)(deg + 1));
        float vx = acc.x * dv, vy = acc.y * dv;
        pre2[n * 64 + lane] = make_float2(vx, vy);
        csx += vx; csy += vy; ss += vx * vx + vy * vy;
    }

    // block-level reduction, then one atomic per slot into replica blockIdx&15
    atomicAdd(&scol[2 * lane], csx);
    atomicAdd(&scol[2 * lane + 1], csy);
    for (int d = 32; d > 0; d >>= 1) ss += __shfl_down(ss, d);
    if (lane == 0) atomicAdd(&sss, ss);
    __syncthreads();
    int rep = blockIdx.x & (NREP - 1);
    if (threadIdx.x < 128) atomicAdd(&colrep[rep * REPSTRIDE + threadIdx.x], scol[threadIdx.x]);
    if (threadIdx.x == 128) atomicAdd(&ssrep[rep], sss);
}

// ---------------------------------------------------------------------------
// K8: FUSED params + apply. Each block sums the 16 replicas to derive m[j]
// and s (all L2-hot), then: y=(v-m_j)*s; out = y>0 ? 2y : y.
__global__ void final_kernel(float* __restrict__ out, const float* __restrict__ colrep,
                             const float* __restrict__ ssrep, int N, int total) {
    __shared__ float sm[128];
    __shared__ float red[128];
    __shared__ float sscale;
    int t = threadIdx.x;
    if (t < 128) {
        float cs = 0.f;
#pragma unroll
        for (int r = 0; r < NREP; ++r) cs += colrep[r * REPSTRIDE + t];
        float m = cs / (float)N;
        sm[t] = m;
        red[t] = m * m;
    }
    __syncthreads();
    for (int d = 64; d > 0; d >>= 1) {
        if (t < d) red[t] += red[t + d];
        __syncthreads();
    }
    if (t == 0) {
        float sq = 0.f;
#pragma unroll
        for (int r = 0; r < NREP; ++r) sq += ssrep[r];
        float tot = sq - (float)N * red[0];  // sum (out - m)^2
        sscale = rsqrtf(EPS + tot / (float)N);
    }
    __syncthreads();
    float s = sscale;
    int tid = blockIdx.x * blockDim.x + threadIdx.x;
    int stride = gridDim.x * blockDim.x;
    for (int i = tid; i < total; i += stride) {
        float y = (out[i] - sm[i & 127]) * s;
        out[i] = y > 0.f ? 2.f * y : y;
    }
}

// ---------------------------------------------------------------------------
extern "C" void kernel_launch(void* const* d_in, const int* in_sizes, int n_in,
                              void* d_out, int out_size, void* d_ws, size_t ws_size,
                              hipStream_t stream) {
    const float* x = (const float*)d_in[0];
    const float* W = (const float*)d_in[1];
    const int* ei  = (const int*)d_in[2];
    int N = in_sizes[0] / 128;
    int E = in_sizes[2] / 2;
    const int* row = ei;        // edge_index[0] = source
    const int* col = ei + E;    // edge_index[1] = aggregation target
    float* out = (float*)d_out;

    // workspace layout: ~12.8MB (xsh) + 0.2 (cursor) + 9.6 (csr) ~= 22.8 MB
    __half* xsh      = (__half*)d_ws;                  // N*128 halves (interleaved)
    int*   cursor    = (int*)((float*)d_ws + (size_t)N * 64);  // N      [zeroed]
    float* colrep    = (float*)(cursor + N);           // NREP*REPSTRIDE [zeroed]
    float* ssrep     = colrep + NREP * REPSTRIDE;      // NREP           [zeroed]
    int*   csr       = (int*)(ssrep + NREP);           // N*MAXDEG

    hipMemsetAsync(cursor, 0, (size_t)(N + NREP * REPSTRIDE + NREP) * 4, stream);

    scatter_kernel<<<(E + 255) / 256, 256, 0, stream>>>(row, col, cursor, csr, E);
    gemm_kernel   <<<(N + 63) / 64, 256, 0, stream>>>(x, W, cursor, xsh, N);
    gather_kernel <<<2048, 256, 0, stream>>>((const __half2*)xsh, cursor, csr,
                                             out, colrep, ssrep, N);
    final_kernel  <<<1024, 256, 0, stream>>>(out, colrep, ssrep, N, N * 128);
}

// Round 18
// 172.205 us; speedup vs baseline: 1.4619x; 1.0137x over previous
//
#include <hip/hip_runtime.h>
#include <hip/hip_fp16.h>

#define EPS 1e-5f
#define NREP 16       // colsum/sumsq replicas (breaks the R8/R9 atomic storm)
#define REPSTRIDE 132 // floats per replica row; 132 % 16 = 4 staggers L2 lines
#define MAXDEG 48     // padded-CSR slots/node; deg ~ Poisson(12), P(any>48) ~ 1e-10

typedef _Float16 half8_t __attribute__((ext_vector_type(8)));
typedef float floatx4 __attribute__((ext_vector_type(4)));

// ---------------------------------------------------------------------------
// K1 (R11, FINAL): single-pass padded-CSR build. Fusion with gemm tried twice
// and permanently abandoned (R16 +34us, R18 +80us).
__global__ void scatter_kernel(const int* __restrict__ row, const int* __restrict__ col,
                               int* __restrict__ cursor, int* __restrict__ csr, int E) {
    int e = blockIdx.x * blockDim.x + threadIdx.x;
    if (e < E) {
        int c = col[e];
        int pos = atomicAdd(&cursor[c], 1);
        if (pos < MAXDEG) csr[c * MAXDEG + pos] = row[e];  // guard unreachable in practice
    }
}

// ---------------------------------------------------------------------------
// K4 (R10, FINAL): xs = fp16( (x @ W.T) * dinv[row] ) — MFMA, W staged once
// per block into padded LDS. Interleaved N*128 xsh layout. dinv node-side.
//
// Layouts (m89/m92-verified conventions):
//   A frag (16x32): lane l elem j -> A[l&15][8*(l>>4)+j]
//   B frag (32x16): lane l elem j -> B[8*(l>>4)+j][l&15]
//   D frag (16x16): lane l reg  r -> D[4*(l>>4)+r][l&15]
// LDS = fp16 W row-major, pad to 136 halves (272B stride == 4 mod 32 dwords ->
// conflict-free b128). x zero-reuse -> direct float4 + in-reg cvt.
__global__ __launch_bounds__(256) void gemm_kernel(
    const float* __restrict__ x, const float* __restrict__ W,
    const int* __restrict__ cursor, __half* __restrict__ xsh, int N) {
    __shared__ _Float16 sw[128][136];  // 34.8 KB

    int tid = threadIdx.x;
#pragma unroll
    for (int t = 0; t < 16; ++t) {
        int idx = tid + t * 256;      // [0, 4096)
        int j = idx >> 5;
        int k4 = idx & 31;
        float4 v = ((const float4*)W)[idx];
        _Float16* d = &sw[j][k4 * 4];
        d[0] = (_Float16)v.x; d[1] = (_Float16)v.y;
        d[2] = (_Float16)v.z; d[3] = (_Float16)v.w;
    }
    __syncthreads();

    int w  = tid >> 6;
    int l  = tid & 63;
    int lr = l & 15;
    int kb = l >> 4;

    int rowA = blockIdx.x * 64 + w * 16 + lr;
    const float4* xr = (const float4*)&x[(size_t)min(rowA, N - 1) * 128];

    float4 xv[8];
#pragma unroll
    for (int kk = 0; kk < 4; ++kk) {
        xv[2 * kk]     = xr[8 * kk + 2 * kb];
        xv[2 * kk + 1] = xr[8 * kk + 2 * kb + 1];
    }
    half8_t a[4];
#pragma unroll
    for (int kk = 0; kk < 4; ++kk) {
        float4 v0 = xv[2 * kk], v1 = xv[2 * kk + 1];
        half8_t h;
        h[0] = (_Float16)v0.x; h[1] = (_Float16)v0.y;
        h[2] = (_Float16)v0.z; h[3] = (_Float16)v0.w;
        h[4] = (_Float16)v1.x; h[5] = (_Float16)v1.y;
        h[6] = (_Float16)v1.z; h[7] = (_Float16)v1.w;
        a[kk] = h;
    }

    floatx4 acc[8];
#pragma unroll
    for (int t = 0; t < 8; ++t) acc[t] = (floatx4){0.f, 0.f, 0.f, 0.f};

#pragma unroll
    for (int kk = 0; kk < 4; ++kk) {
#pragma unroll
        for (int t = 0; t < 8; ++t) {
            half8_t b = *(const half8_t*)&sw[16 * t + lr][32 * kk + 8 * kb];
            acc[t] = __builtin_amdgcn_mfma_f32_16x16x32_f16(a[kk], b, acc[t], 0, 0, 0);
        }
    }

    int rbase = blockIdx.x * 64 + w * 16 + 4 * kb;
    float dv[4];
#pragma unroll
    for (int r = 0; r < 4; ++r)
        dv[r] = (rbase + r < N) ? rsqrtf((float)(cursor[rbase + r] + 1)) : 0.f;
#pragma unroll
    for (int r = 0; r < 4; ++r) {
        int grow = rbase + r;
        if (grow < N) {
#pragma unroll
            for (int t = 0; t < 8; ++t)
                xsh[(size_t)grow * 128 + 16 * t + lr] = __float2half(acc[t][r] * dv[r]);
        }
    }
}

// ---------------------------------------------------------------------------
// K5 (R21): DEPTH-2 pipelined gather. Ladder: R11 52us -> R15 clamped-16
// 48.5us (intra-node tail) -> R20 index-prefetch 44.5us (prologue chain).
// Remaining exposed latency: batch-0 VALUE loads were issued+consumed in the
// same iteration. Depth-2 fix: indices for node n+nw arrived a full iteration
// ago, so deg is known AT ISSUE TIME -> issue n+nw's validated value loads
// while consuming node n's values. Steady state: every load class has one
// full iteration to retire; per-node cost ~ issue-limited.
// Stages: [index: iDeg,iSelf,iIdx for n+nw] -> [value: vDeg,vSelf,vVals for n]
// VGPR ~90 (5 waves/SIMD) — ILP-for-TLP trade, valid in latency-bound regime.
// deg>16 tail (~10% nodes): clamped direct path. e==0-safe via 'safe' base.
// Pre-commit: gather >= 44us -> roofline at best-known.
__global__ void gather_kernel(const __half2* __restrict__ xs2, const int* __restrict__ cursor,
                              const int* __restrict__ csr,
                              float* __restrict__ pre, float* __restrict__ colrep,
                              float* __restrict__ ssrep, int N) {
    __shared__ float scol[128];
    __shared__ float sss;
    if (threadIdx.x < 128) scol[threadIdx.x] = 0.f;
    if (threadIdx.x == 0) sss = 0.f;
    __syncthreads();

    int lane = threadIdx.x & 63;
    int wid = (blockIdx.x * blockDim.x + threadIdx.x) >> 6;
    int nw  = (gridDim.x * blockDim.x) >> 6;
    float2* pre2 = (float2*)pre;
    float csx = 0.f, csy = 0.f, ss = 0.f;

    // ---- pipeline state ----
    int iDeg = 0; __half2 iSelf = __half2{}; int iIdx[16];   // index stage (node n+nw)
    int vDeg = 0; __half2 vSelf = __half2{}; __half2 vVals[16]; // value stage (node n)
#pragma unroll
    for (int t = 0; t < 16; ++t) iIdx[t] = 0;
#pragma unroll
    for (int t = 0; t < 16; ++t) vVals[t] = __half2{};

    // ---- prime: indices for node wid, then promote to values; indices for wid+nw
    if (wid < N) {
        iDeg = cursor[wid];
        iSelf = xs2[wid * 64 + lane];
        const int* cs0 = &csr[wid * MAXDEG];
#pragma unroll
        for (int t = 0; t < 16; ++t) iIdx[t] = cs0[t];
        int e0 = min(iDeg, MAXDEG);
        int safe = (e0 > 0) ? iIdx[0] : wid;
        vDeg = iDeg; vSelf = iSelf;
#pragma unroll
        for (int t = 0; t < 16; ++t)
            vVals[t] = xs2[((t < e0) ? iIdx[t] : safe) * 64 + lane];
        int n1 = wid + nw;
        if (n1 < N) {
            iDeg = cursor[n1];
            iSelf = xs2[n1 * 64 + lane];
            const int* cs1 = &csr[n1 * MAXDEG];
#pragma unroll
            for (int t = 0; t < 16; ++t) iIdx[t] = cs1[t];
        }
    }

    for (int n = wid; n < N; n += nw) {
        // ---- consume value stage (node n) ----
        int deg = vDeg;
        int e = min(deg, MAXDEG);
        float2 acc = __half22float2(vSelf);
#pragma unroll
        for (int t = 0; t < 16; ++t) {
            float m = (t < e) ? 1.f : 0.f;
            float2 f = __half22float2(vVals[t]);
            acc.x += m * f.x; acc.y += m * f.y;
        }
        // tail batches (deg > 16, ~10% of nodes): clamped direct path
        if (e > 16) {
            const int* cs = &csr[n * MAXDEG];
            for (int base = 16; base < e; base += 16) {
                int idx[16];
#pragma unroll
                for (int t = 0; t < 16; ++t) idx[t] = cs[min(base + t, e - 1)];
                __half2 b[16];
#pragma unroll
                for (int t = 0; t < 16; ++t) b[t] = xs2[idx[t] * 64 + lane];
#pragma unroll
                for (int t = 0; t < 16; ++t) {
                    float m = (base + t < e) ? 1.f : 0.f;
                    float2 f = __half22float2(b[t]);
                    acc.x += m * f.x; acc.y += m * f.y;
                }
            }
        }

        // ---- promote index stage -> value stage (node n+nw) ----
        int nn = n + nw;
        if (nn < N) {
            int e1 = min(iDeg, MAXDEG);
            int safe = (e1 > 0) ? iIdx[0] : nn;
            vDeg = iDeg; vSelf = iSelf;
#pragma unroll
            for (int t = 0; t < 16; ++t)
                vVals[t] = xs2[((t < e1) ? iIdx[t] : safe) * 64 + lane];
        }
        // ---- prefetch index stage (node n+2nw) ----
        int n2 = n + 2 * nw;
        if (n2 < N) {
            iDeg = cursor[n2];
            iSelf = xs2[n2 * 64 + lane];
            const int* cs2 = &csr[n2 * MAXDEG];
#pragma unroll
            for (int t = 0; t < 16; ++t) iIdx[t] = cs2[t];
        }

        // ---- epilogue for node n ----
        float dv = rsqrtf((float)(deg + 1));
        float vx = acc.x * dv, vy = acc.y * dv;
        pre2[n * 64 + lane] = make_float2(vx, vy);
        csx += vx; csy += vy; ss += vx * vx + vy * vy;
    }

    // block-level reduction, then one atomic per slot into replica blockIdx&15
    atomicAdd(&scol[2 * lane], csx);
    atomicAdd(&scol[2 * lane + 1], csy);
    for (int d = 32; d > 0; d >>= 1) ss += __shfl_down(ss, d);
    if (lane == 0) atomicAdd(&sss, ss);
    __syncthreads();
    int rep = blockIdx.x & (NREP - 1);
    if (threadIdx.x < 128) atomicAdd(&colrep[rep * REPSTRIDE + threadIdx.x], scol[threadIdx.x]);
    if (threadIdx.x == 128) atomicAdd(&ssrep[rep], sss);
}

// ---------------------------------------------------------------------------
// K8: FUSED params + apply.
__global__ void final_kernel(float* __restrict__ out, const float* __restrict__ colrep,
                             const float* __restrict__ ssrep, int N, int total) {
    __shared__ float sm[128];
    __shared__ float red[128];
    __shared__ float sscale;
    int t = threadIdx.x;
    if (t < 128) {
        float cs = 0.f;
#pragma unroll
        for (int r = 0; r < NREP; ++r) cs += colrep[r * REPSTRIDE + t];
        float m = cs / (float)N;
        sm[t] = m;
        red[t] = m * m;
    }
    __syncthreads();
    for (int d = 64; d > 0; d >>= 1) {
        if (t < d) red[t] += red[t + d];
        __syncthreads();
    }
    if (t == 0) {
        float sq = 0.f;
#pragma unroll
        for (int r = 0; r < NREP; ++r) sq += ssrep[r];
        float tot = sq - (float)N * red[0];  // sum (out - m)^2
        sscale = rsqrtf(EPS + tot / (float)N);
    }
    __syncthreads();
    float s = sscale;
    int tid = blockIdx.x * blockDim.x + threadIdx.x;
    int stride = gridDim.x * blockDim.x;
    for (int i = tid; i < total; i += stride) {
        float y = (out[i] - sm[i & 127]) * s;
        out[i] = y > 0.f ? 2.f * y : y;
    }
}

// ---------------------------------------------------------------------------
extern "C" void kernel_launch(void* const* d_in, const int* in_sizes, int n_in,
                              void* d_out, int out_size, void* d_ws, size_t ws_size,
                              hipStream_t stream) {
    const float* x = (const float*)d_in[0];
    const float* W = (const float*)d_in[1];
    const int* ei  = (const int*)d_in[2];
    int N = in_sizes[0] / 128;
    int E = in_sizes[2] / 2;
    const int* row = ei;        // edge_index[0] = source
    const int* col = ei + E;    // edge_index[1] = aggregation target
    float* out = (float*)d_out;

    // workspace layout: ~12.8MB (xsh) + 0.2 (cursor) + 9.6 (csr) ~= 22.8 MB
    __half* xsh      = (__half*)d_ws;                  // N*128 halves (interleaved)
    int*   cursor    = (int*)((float*)d_ws + (size_t)N * 64);  // N      [zeroed]
    float* colrep    = (float*)(cursor + N);           // NREP*REPSTRIDE [zeroed]
    float* ssrep     = colrep + NREP * REPSTRIDE;      // NREP           [zeroed]
    int*   csr       = (int*)(ssrep + NREP);           // N*MAXDEG

    hipMemsetAsync(cursor, 0, (size_t)(N + NREP * REPSTRIDE + NREP) * 4, stream);

    scatter_kernel<<<(E + 255) / 256, 256, 0, stream>>>(row, col, cursor, csr, E);
    gemm_kernel   <<<(N + 63) / 64, 256, 0, stream>>>(x, W, cursor, xsh, N);
    gather_kernel <<<2048, 256, 0, stream>>>((const __half2*)xsh, cursor, csr,
                                             out, colrep, ssrep, N);
    final_kernel  <<<1024, 256, 0, stream>>>(out, colrep, ssrep, N, N * 128);
}